// Round 15
// baseline (48.168 us; speedup 1.0000x reference)
//
#include <hip/hip_runtime.h>

#define B_  4
#define NQ_ 256
#define NK_ 512
#define H_  256
#define PADE 516   // float4s per E row (512 + 4 pad): stride 8256B, not 8KB

// 2*log2(e): exp2(x*TWO_LOG2E) = e^{2x}
#define TWO_LOG2E 2.8853900817779268f

// Round-13 gemm (best known): 64x64 tiles, 192 blocks, reg-dbuf staging.
//   blocks [0,128):  E[b][o>>2][k][o&3] = e^{2*kt[b][o][k]}   (padded rows)
//   blocks [128,192): F[b][q][o]        = e^{2*qt[b][q][o]}
__global__ __launch_bounds__(256)
void gemm_fused(const float* __restrict__ xq, const float* __restrict__ xk,
                const float* __restrict__ w1, const float* __restrict__ w2,
                float* __restrict__ Ebuf,    // [B][64][PADE*4] floats
                float* __restrict__ Fbuf)    // [B][NQ][H]
{
    constexpr int BK = 32;
    const float* A; const float* Bm;
    int m0, n0, bz; bool iskt;
    {
        int id = blockIdx.x;
        if (id < 128) {
            iskt = true;
            bz = id >> 5; int t = id & 31;
            m0 = (t >> 3) * 64; n0 = (t & 7) * 64;
            A = w1; Bm = xk + (long)bz * NK_ * H_;
        } else {
            iskt = false;
            id -= 128;
            bz = id >> 4; int t = id & 15;
            m0 = (t >> 2) * 64; n0 = (t & 3) * 64;
            A = xq + (long)bz * NQ_ * H_; Bm = w2;
        }
    }
    const int lda = H_, ldb = H_;

    __shared__ float As[BK][68];
    __shared__ float Bs[BK][68];

    const int tid  = threadIdx.x;
    const int lrow = tid >> 2;
    const int lk   = (tid & 3) * 8;
    const int tm   = (tid >> 4) * 4;
    const int tn   = (tid & 15) * 4;

    float acc[4][4] = {};

    float4 a0_r = *(const float4*)&A [(long)(m0 + lrow) * lda + lk];
    float4 a1_r = *(const float4*)&A [(long)(m0 + lrow) * lda + lk + 4];
    float4 b0_r = *(const float4*)&Bm[(long)(n0 + lrow) * ldb + lk];
    float4 b1_r = *(const float4*)&Bm[(long)(n0 + lrow) * ldb + lk + 4];
    float4 a0_n = a0_r, a1_n = a1_r, b0_n = b0_r, b1_n = b1_r;

    for (int kt = 0; kt < H_; kt += BK) {
        __syncthreads();
        As[lk+0][lrow]=a0_r.x; As[lk+1][lrow]=a0_r.y; As[lk+2][lrow]=a0_r.z; As[lk+3][lrow]=a0_r.w;
        As[lk+4][lrow]=a1_r.x; As[lk+5][lrow]=a1_r.y; As[lk+6][lrow]=a1_r.z; As[lk+7][lrow]=a1_r.w;
        Bs[lk+0][lrow]=b0_r.x; Bs[lk+1][lrow]=b0_r.y; Bs[lk+2][lrow]=b0_r.z; Bs[lk+3][lrow]=b0_r.w;
        Bs[lk+4][lrow]=b1_r.x; Bs[lk+5][lrow]=b1_r.y; Bs[lk+6][lrow]=b1_r.z; Bs[lk+7][lrow]=b1_r.w;
        if (kt + BK < H_) {
            a0_n = *(const float4*)&A [(long)(m0 + lrow) * lda + kt + BK + lk];
            a1_n = *(const float4*)&A [(long)(m0 + lrow) * lda + kt + BK + lk + 4];
            b0_n = *(const float4*)&Bm[(long)(n0 + lrow) * ldb + kt + BK + lk];
            b1_n = *(const float4*)&Bm[(long)(n0 + lrow) * ldb + kt + BK + lk + 4];
        }
        __syncthreads();
        #pragma unroll
        for (int kk = 0; kk < BK; ++kk) {
            float4 av = *(const float4*)&As[kk][tm];
            float4 bv = *(const float4*)&Bs[kk][tn];
            float am[4] = {av.x, av.y, av.z, av.w};
            float bn[4] = {bv.x, bv.y, bv.z, bv.w};
            #pragma unroll
            for (int i = 0; i < 4; ++i)
                #pragma unroll
                for (int j = 0; j < 4; ++j)
                    acc[i][j] = fmaf(am[i], bn[j], acc[i][j]);
        }
        a0_r = a0_n; a1_r = a1_n; b0_r = b0_n; b1_r = b1_n;
    }

    if (iskt) {
        float4* cb = (float4*)Ebuf + ((long)bz * 64 + ((m0 + tm) >> 2)) * PADE;
        #pragma unroll
        for (int j = 0; j < 4; ++j) {
            float4 e4 = { __builtin_amdgcn_exp2f(acc[0][j] * TWO_LOG2E),
                          __builtin_amdgcn_exp2f(acc[1][j] * TWO_LOG2E),
                          __builtin_amdgcn_exp2f(acc[2][j] * TWO_LOG2E),
                          __builtin_amdgcn_exp2f(acc[3][j] * TWO_LOG2E) };
            cb[n0 + tn + j] = e4;
        }
    } else {
        #pragma unroll
        for (int i = 0; i < 4; ++i) {
            float4 f4v = { __builtin_amdgcn_exp2f(acc[i][0] * TWO_LOG2E),
                           __builtin_amdgcn_exp2f(acc[i][1] * TWO_LOG2E),
                           __builtin_amdgcn_exp2f(acc[i][2] * TWO_LOG2E),
                           __builtin_amdgcn_exp2f(acc[i][3] * TWO_LOG2E) };
            *(float4*)&Fbuf[((long)bz * NQ_ + m0 + tm + i) * H_ + n0 + tn] = f4v;
        }
    }
}

// MODE 0: full round-13 attn. MODE 3: ABLATION -- identical E-load stream,
// prefetch structure, grid, epilogue; all QTERM math and F/v s_loads removed
// (3 adds per float4 keep loads live). Writes scratch, not out.
// Round total = 38.2 + t_mode3 disambiguates E-stream-bound vs math-bound.
template<int MODE>
__global__ __launch_bounds__(512, 2)
void attn_main(const float4* __restrict__ E4,   // [B][64][PADE]
               const float* __restrict__ Fbuf,  // [B][NQ][H]
               const float* __restrict__ v,     // [H]
               float* __restrict__ outp)        // [B][NQ][NK]
{
    const int k = threadIdx.x, b = blockIdx.y, q0 = blockIdx.x * 2;

    const float4* kp  = E4 + (long)b * 64 * PADE + k;
    const float4* F0p = (const float4*)(Fbuf + ((long)b * NQ_ + q0) * H_);
    const float4* F1p = F0p + (H_ / 4);
    const float4* v4p = (const float4*)v;

    float T0 = 0.f, T1 = 0.f;

    float4 ka0 = kp[0*PADE], ka1 = kp[1*PADE], ka2 = kp[2*PADE], ka3 = kp[3*PADE];
    float4 kb0 = kp[4*PADE], kb1 = kp[5*PADE], kb2 = kp[6*PADE], kb3 = kp[7*PADE];
    float4 kc0 = ka0, kc1 = ka1, kc2 = ka2, kc3 = ka3;

#define PROC4(EV, HC)                                                         \
    if (MODE == 0) {                                                          \
        float4 f0 = F0p[HC];             /* uniform -> s_load_dwordx4 */      \
        float4 f1 = F1p[HC];                                                  \
        float4 vv = v4p[HC];                                                  \
        {   /* q0 */                                                          \
            float d0 = fmaf(EV.x, f0.x, 1.f), d1 = fmaf(EV.y, f0.y, 1.f);     \
            float d2 = fmaf(EV.z, f0.z, 1.f), d3 = fmaf(EV.w, f0.w, 1.f);     \
            float D01 = d0 * d1, D23 = d2 * d3;                               \
            float N01 = fmaf(vv.x, d1, vv.y * d0);                            \
            float N23 = fmaf(vv.z, d3, vv.w * d2);                            \
            float N   = fmaf(N01, D23, N23 * D01);                            \
            T0 = fmaf(N, __builtin_amdgcn_rcpf(D01 * D23), T0);               \
        }                                                                     \
        {   /* q1 */                                                          \
            float d0 = fmaf(EV.x, f1.x, 1.f), d1 = fmaf(EV.y, f1.y, 1.f);     \
            float d2 = fmaf(EV.z, f1.z, 1.f), d3 = fmaf(EV.w, f1.w, 1.f);     \
            float D01 = d0 * d1, D23 = d2 * d3;                               \
            float N01 = fmaf(vv.x, d1, vv.y * d0);                            \
            float N23 = fmaf(vv.z, d3, vv.w * d2);                            \
            float N   = fmaf(N01, D23, N23 * D01);                            \
            T1 = fmaf(N, __builtin_amdgcn_rcpf(D01 * D23), T1);               \
        }                                                                     \
    } else {                                                                  \
        T0 += (EV.x + EV.y) + (EV.z + EV.w);   /* keep load live, min VALU */ \
    }

    for (int g = 0; g < 64; g += 4) {
        if (g + 8 < 64) {
            kc0 = kp[(long)(g +  8) * PADE];
            kc1 = kp[(long)(g +  9) * PADE];
            kc2 = kp[(long)(g + 10) * PADE];
            kc3 = kp[(long)(g + 11) * PADE];
        }
        PROC4(ka0, g + 0)
        PROC4(ka1, g + 1)
        PROC4(ka2, g + 2)
        PROC4(ka3, g + 3)
        ka0 = kb0; ka1 = kb1; ka2 = kb2; ka3 = kb3;
        kb0 = kc0; kb1 = kc1; kb2 = kc2; kb3 = kc3;
    }
#undef PROC4

    float val0 = -2.f * T0;
    float val1 = -2.f * T1;

    __shared__ float red[8][2];
    const int lane = k & 63, wv = k >> 6;

    float e0 = __builtin_amdgcn_exp2f(val0 * 1.4426950408889634f);
    float e1 = __builtin_amdgcn_exp2f(val1 * 1.4426950408889634f);
    #pragma unroll
    for (int o = 32; o; o >>= 1) {
        e0 += __shfl_xor(e0, o, 64);
        e1 += __shfl_xor(e1, o, 64);
    }
    if (lane == 0) { red[wv][0] = e0; red[wv][1] = e1; }
    __syncthreads();
    float s0 = 0.f, s1 = 0.f;
    #pragma unroll
    for (int w = 0; w < 8; ++w) { s0 += red[w][0]; s1 += red[w][1]; }

    float l0 = __builtin_amdgcn_logf(s0) * 0.6931471805599453f;
    float l1 = __builtin_amdgcn_logf(s1) * 0.6931471805599453f;
    outp[((long)b * NQ_ + q0 + 0) * NK_ + k] = val0 - l0;
    outp[((long)b * NQ_ + q0 + 1) * NK_ + k] = val1 - l1;
}

extern "C" void kernel_launch(void* const* d_in, const int* in_sizes, int n_in,
                              void* d_out, int out_size, void* d_ws, size_t ws_size,
                              hipStream_t stream)
{
    const float* xq = (const float*)d_in[0];  // (4,256,256)
    const float* xk = (const float*)d_in[1];  // (4,512,256)
    const float* w1 = (const float*)d_in[2];  // (256,256) out,in
    const float* w2 = (const float*)d_in[3];  // (256,256)
    const float* v  = (const float*)d_in[4];  // (1,256)
    float* out = (float*)d_out;

    float* Ebuf = (float*)d_ws;                             // ~2.11 MB
    float* Fbuf = Ebuf + (size_t)B_ * 64 * PADE * 4;        // 1 MB
    float* scratch = Fbuf + (size_t)B_ * NQ_ * H_;          // 2 MB ablation sink

    gemm_fused<<<dim3(192), 256, 0, stream>>>(xq, xk, w1, w2, Ebuf, Fbuf);
    // real result
    attn_main<0><<<dim3(NQ_ / 2, B_), 512, 0, stream>>>(
        (const float4*)Ebuf, Fbuf, v, out);
    // ABLATION: E-load stream only (same grid/prefetch), writes scratch.
    // total - 38.2 = cost of the bare E stream. Remove next round.
    attn_main<3><<<dim3(NQ_ / 2, B_), 512, 0, stream>>>(
        (const float4*)Ebuf, Fbuf, v, scratch);
}

// Round 16
// 38.125 us; speedup vs baseline: 1.2634x; 1.2634x over previous
//
#include <hip/hip_runtime.h>

#define B_  4
#define NQ_ 256
#define NK_ 512
#define H_  256
#define PADE 516   // float4s per E row (512 + 4 pad): stride 8256B, not 8KB

// 2*log2(e): exp2(x*TWO_LOG2E) = e^{2x}
#define TWO_LOG2E 2.8853900817779268f

// 32x64 tiles, 384 blocks (1.5 blocks/CU -- r14 showed this cuts gemm ~17->10
// vs 192x 64x64 blocks), 256 threads, 8 outputs/thread, reg-dbuf staging.
//   blocks [0,256):  E[b][o>>2][k][o&3] = e^{2*kt[b][o][k]}   (padded rows)
//   blocks [256,384): F[b][q][o]        = e^{2*qt[b][q][o]}
// tanh(a+b) = 1 - 2/(1 + e^{2a}e^{2b}) is EXACT; d >= 1 always.
__global__ __launch_bounds__(256)
void gemm_fused(const float* __restrict__ xq, const float* __restrict__ xk,
                const float* __restrict__ w1, const float* __restrict__ w2,
                float* __restrict__ Ebuf,    // [B][64][PADE*4] floats
                float* __restrict__ Fbuf)    // [B][NQ][H]
{
    constexpr int BK = 32;
    const float* A; const float* Bm;
    int m0, n0, bz; bool iskt;
    {
        int id = blockIdx.x;
        if (id < 256) {                      // kt: M=H(o) 8 tiles, N=NK(k) 8 tiles
            iskt = true;
            bz = id >> 6; int t = id & 63;
            m0 = (t >> 3) * 32; n0 = (t & 7) * 64;
            A = w1; Bm = xk + (long)bz * NK_ * H_;
        } else {                             // qt: M=NQ(q) 8 tiles, N=H(o) 4 tiles
            iskt = false;
            id -= 256;
            bz = id >> 5; int t = id & 31;
            m0 = (t >> 2) * 32; n0 = (t & 3) * 64;
            A = xq + (long)bz * NQ_ * H_; Bm = w2;
        }
    }
    const int lda = H_, ldb = H_;

    __shared__ float As[BK][36];
    __shared__ float Bs[BK][68];

    const int tid  = threadIdx.x;
    const int arow = tid >> 3, ak = (tid & 7) * 4;   // 32 rows x 32 k
    const int brow = tid >> 2, bk = (tid & 3) * 8;   // 64 rows x 32 k
    const int tm = (tid >> 5) * 4;       // 0..28
    const int tn = (tid & 31) * 2;       // 0..62

    float acc[4][2] = {};

    float4 a_r  = *(const float4*)&A [(long)(m0 + arow) * lda + ak];
    float4 b0_r = *(const float4*)&Bm[(long)(n0 + brow) * ldb + bk];
    float4 b1_r = *(const float4*)&Bm[(long)(n0 + brow) * ldb + bk + 4];
    float4 a_n = a_r, b0_n = b0_r, b1_n = b1_r;

    for (int kt = 0; kt < H_; kt += BK) {
        __syncthreads();
        As[ak+0][arow]=a_r.x; As[ak+1][arow]=a_r.y; As[ak+2][arow]=a_r.z; As[ak+3][arow]=a_r.w;
        Bs[bk+0][brow]=b0_r.x; Bs[bk+1][brow]=b0_r.y; Bs[bk+2][brow]=b0_r.z; Bs[bk+3][brow]=b0_r.w;
        Bs[bk+4][brow]=b1_r.x; Bs[bk+5][brow]=b1_r.y; Bs[bk+6][brow]=b1_r.z; Bs[bk+7][brow]=b1_r.w;
        if (kt + BK < H_) {
            a_n  = *(const float4*)&A [(long)(m0 + arow) * lda + kt + BK + ak];
            b0_n = *(const float4*)&Bm[(long)(n0 + brow) * ldb + kt + BK + bk];
            b1_n = *(const float4*)&Bm[(long)(n0 + brow) * ldb + kt + BK + bk + 4];
        }
        __syncthreads();
        #pragma unroll
        for (int kk = 0; kk < BK; ++kk) {
            float4 av = *(const float4*)&As[kk][tm];
            float2 bv = *(const float2*)&Bs[kk][tn];
            float am[4] = {av.x, av.y, av.z, av.w};
            #pragma unroll
            for (int i = 0; i < 4; ++i) {
                acc[i][0] = fmaf(am[i], bv.x, acc[i][0]);
                acc[i][1] = fmaf(am[i], bv.y, acc[i][1]);
            }
        }
        a_r = a_n; b0_r = b0_n; b1_r = b1_n;
    }

    if (iskt) {
        float4* cb = (float4*)Ebuf + ((long)bz * 64 + ((m0 + tm) >> 2)) * PADE;
        #pragma unroll
        for (int j = 0; j < 2; ++j) {
            float4 e4 = { __builtin_amdgcn_exp2f(acc[0][j] * TWO_LOG2E),
                          __builtin_amdgcn_exp2f(acc[1][j] * TWO_LOG2E),
                          __builtin_amdgcn_exp2f(acc[2][j] * TWO_LOG2E),
                          __builtin_amdgcn_exp2f(acc[3][j] * TWO_LOG2E) };
            cb[n0 + tn + j] = e4;
        }
    } else {
        #pragma unroll
        for (int i = 0; i < 4; ++i) {
            float2 f2v = { __builtin_amdgcn_exp2f(acc[i][0] * TWO_LOG2E),
                           __builtin_amdgcn_exp2f(acc[i][1] * TWO_LOG2E) };
            *(float2*)&Fbuf[((long)bz * NQ_ + m0 + tm + i) * H_ + n0 + tn] = f2v;
        }
    }
}

// One block per (b, 2 q-rows), 512 threads = one per k.
// prod[q,k] = -2 * sum_h v[h] / (1 + E[h,k]*F[q,h])   (Sum v cancels in LSM)
// r15 ablation: E-stream = 10us, math+F-scalar = 11us, mostly SERIAL because
// F/v s_loads issue at point-of-use. Fix: software-pipeline the scalar
// operands ONE sub-iteration ahead into named sets (6 dwordx4 in flight).
// E keeps the 8-deep vector prefetch.
__global__ __launch_bounds__(512, 2)
void attn_main(const float4* __restrict__ E4,   // [B][64][PADE]
               const float* __restrict__ Fbuf,  // [B][NQ][H]
               const float* __restrict__ v,     // [H]
               float* __restrict__ out)         // [B][NQ][NK]
{
    const int k = threadIdx.x, b = blockIdx.y, q0 = blockIdx.x * 2;

    const float4* kp  = E4 + (long)b * 64 * PADE + k;
    const float4* F0p = (const float4*)(Fbuf + ((long)b * NQ_ + q0) * H_);
    const float4* F1p = F0p + (H_ / 4);
    const float4* v4p = (const float4*)v;

    float T0 = 0.f, T1 = 0.f;

    // E: 8-deep prefetch (A = current group, B = next, C = landing)
    float4 ka0 = kp[0*PADE], ka1 = kp[1*PADE], ka2 = kp[2*PADE], ka3 = kp[3*PADE];
    float4 kb0 = kp[4*PADE], kb1 = kp[5*PADE], kb2 = kp[6*PADE], kb3 = kp[7*PADE];
    float4 kc0 = ka0, kc1 = ka1, kc2 = ka2, kc3 = ka3;

    // scalar operands: current set + next set (prefetched 1 sub-iter ahead)
    float4 sf0 = F0p[0], sf1 = F1p[0], sv = v4p[0];
    float4 nf0, nf1, nv;

#define QPAIR(EV)                                                             \
    {                                                                         \
        {   /* q0 */                                                          \
            float d0 = fmaf(EV.x, sf0.x, 1.f), d1 = fmaf(EV.y, sf0.y, 1.f);   \
            float d2 = fmaf(EV.z, sf0.z, 1.f), d3 = fmaf(EV.w, sf0.w, 1.f);   \
            float D01 = d0 * d1, D23 = d2 * d3;                               \
            float N01 = fmaf(sv.x, d1, sv.y * d0);                            \
            float N23 = fmaf(sv.z, d3, sv.w * d2);                            \
            float N   = fmaf(N01, D23, N23 * D01);                            \
            T0 = fmaf(N, __builtin_amdgcn_rcpf(D01 * D23), T0);               \
        }                                                                     \
        {   /* q1 */                                                          \
            float d0 = fmaf(EV.x, sf1.x, 1.f), d1 = fmaf(EV.y, sf1.y, 1.f);   \
            float d2 = fmaf(EV.z, sf1.z, 1.f), d3 = fmaf(EV.w, sf1.w, 1.f);   \
            float D01 = d0 * d1, D23 = d2 * d3;                               \
            float N01 = fmaf(sv.x, d1, sv.y * d0);                            \
            float N23 = fmaf(sv.z, d3, sv.w * d2);                            \
            float N   = fmaf(N01, D23, N23 * D01);                            \
            T1 = fmaf(N, __builtin_amdgcn_rcpf(D01 * D23), T1);               \
        }                                                                     \
    }
#define SROT() sf0 = nf0; sf1 = nf1; sv = nv;

    for (int g = 0; g < 64; g += 4) {
        if (g + 8 < 64) {          // land E rows g+8..g+11 in C
            kc0 = kp[(long)(g +  8) * PADE];
            kc1 = kp[(long)(g +  9) * PADE];
            kc2 = kp[(long)(g + 10) * PADE];
            kc3 = kp[(long)(g + 11) * PADE];
        }
        nf0 = F0p[g + 1]; nf1 = F1p[g + 1]; nv = v4p[g + 1];   // issue early
        QPAIR(ka0) SROT()
        nf0 = F0p[g + 2]; nf1 = F1p[g + 2]; nv = v4p[g + 2];
        QPAIR(ka1) SROT()
        nf0 = F0p[g + 3]; nf1 = F1p[g + 3]; nv = v4p[g + 3];
        QPAIR(ka2) SROT()
        { const int gn = (g + 4) & 63;                          // wrap-safe
          nf0 = F0p[gn]; nf1 = F1p[gn]; nv = v4p[gn]; }
        QPAIR(ka3) SROT()
        ka0 = kb0; ka1 = kb1; ka2 = kb2; ka3 = kb3;
        kb0 = kc0; kb1 = kc1; kb2 = kc2; kb3 = kc3;
    }
#undef QPAIR
#undef SROT

    float val0 = -2.f * T0;
    float val1 = -2.f * T1;

    // ---- log-softmax over k, no max pass (|val| <= 2*sum|v| ~ 16, safe) ----
    __shared__ float red[8][2];
    const int lane = k & 63, wv = k >> 6;

    float e0 = __builtin_amdgcn_exp2f(val0 * 1.4426950408889634f);
    float e1 = __builtin_amdgcn_exp2f(val1 * 1.4426950408889634f);
    #pragma unroll
    for (int o = 32; o; o >>= 1) {
        e0 += __shfl_xor(e0, o, 64);
        e1 += __shfl_xor(e1, o, 64);
    }
    if (lane == 0) { red[wv][0] = e0; red[wv][1] = e1; }
    __syncthreads();
    float s0 = 0.f, s1 = 0.f;
    #pragma unroll
    for (int w = 0; w < 8; ++w) { s0 += red[w][0]; s1 += red[w][1]; }

    float l0 = __builtin_amdgcn_logf(s0) * 0.6931471805599453f;  // ln(s0)
    float l1 = __builtin_amdgcn_logf(s1) * 0.6931471805599453f;
    out[((long)b * NQ_ + q0 + 0) * NK_ + k] = val0 - l0;
    out[((long)b * NQ_ + q0 + 1) * NK_ + k] = val1 - l1;
}

extern "C" void kernel_launch(void* const* d_in, const int* in_sizes, int n_in,
                              void* d_out, int out_size, void* d_ws, size_t ws_size,
                              hipStream_t stream)
{
    const float* xq = (const float*)d_in[0];  // (4,256,256)
    const float* xk = (const float*)d_in[1];  // (4,512,256)
    const float* w1 = (const float*)d_in[2];  // (256,256) out,in
    const float* w2 = (const float*)d_in[3];  // (256,256)
    const float* v  = (const float*)d_in[4];  // (1,256)
    float* out = (float*)d_out;

    float* Ebuf = (float*)d_ws;                             // ~2.11 MB
    float* Fbuf = Ebuf + (size_t)B_ * 64 * PADE * 4;        // 1 MB

    gemm_fused<<<dim3(384), 256, 0, stream>>>(xq, xk, w1, w2, Ebuf, Fbuf);
    attn_main<<<dim3(NQ_ / 2, B_), 512, 0, stream>>>(
        (const float4*)Ebuf, Fbuf, v, out);
}

// Round 17
// 35.367 us; speedup vs baseline: 1.3620x; 1.0780x over previous
//
#include <hip/hip_runtime.h>

#define B_  4
#define NQ_ 256
#define NK_ 512
#define H_  256
#define PADK 520   // half8s per E row: stride 520*16B = 8320B, breaks 8KB aliasing

typedef _Float16 half8  __attribute__((ext_vector_type(8)));
typedef _Float16 half4_t __attribute__((ext_vector_type(4)));

// 2*log2(e): exp2(x*TWO_LOG2E) = e^{2x}
#define TWO_LOG2E 2.8853900817779268f

// r13 gemm (64x64 tiles, 192 blocks, reg-dbuf). Epilogues store EXP:
//   blocks [0,128):  E[b][o>>3][k][o&7] = fp16(e^{2*kt[b][o][k]})
//   blocks [128,192): F[b][q][o]        = f32 e^{2*qt[b][q][o]}
// tanh(a+b) = 1 - 2/(1 + e^{2a}e^{2b}) exact; E fits fp16 (|2kt|<~6 => <330).
__global__ __launch_bounds__(256)
void gemm_fused(const float* __restrict__ xq, const float* __restrict__ xk,
                const float* __restrict__ w1, const float* __restrict__ w2,
                _Float16* __restrict__ Ebuf,  // [B][32][PADK][8] halves
                float* __restrict__ Fbuf)     // [B][NQ][H]
{
    constexpr int BK = 32;
    const float* A; const float* Bm;
    int m0, n0, bz; bool iskt;
    {
        int id = blockIdx.x;
        if (id < 128) {                      // kt: M=H(o), N=NK(k)
            iskt = true;
            bz = id >> 5; int t = id & 31;
            m0 = (t >> 3) * 64; n0 = (t & 7) * 64;
            A = w1; Bm = xk + (long)bz * NK_ * H_;
        } else {                             // qt: M=NQ(q), N=H(o)
            iskt = false;
            id -= 128;
            bz = id >> 4; int t = id & 15;
            m0 = (t >> 2) * 64; n0 = (t & 3) * 64;
            A = xq + (long)bz * NQ_ * H_; Bm = w2;
        }
    }
    const int lda = H_, ldb = H_;

    __shared__ float As[BK][68];
    __shared__ float Bs[BK][68];

    const int tid  = threadIdx.x;
    const int lrow = tid >> 2;
    const int lk   = (tid & 3) * 8;
    const int tm   = (tid >> 4) * 4;
    const int tn   = (tid & 15) * 4;

    float acc[4][4] = {};

    float4 a0_r = *(const float4*)&A [(long)(m0 + lrow) * lda + lk];
    float4 a1_r = *(const float4*)&A [(long)(m0 + lrow) * lda + lk + 4];
    float4 b0_r = *(const float4*)&Bm[(long)(n0 + lrow) * ldb + lk];
    float4 b1_r = *(const float4*)&Bm[(long)(n0 + lrow) * ldb + lk + 4];
    float4 a0_n = a0_r, a1_n = a1_r, b0_n = b0_r, b1_n = b1_r;

    for (int kt = 0; kt < H_; kt += BK) {
        __syncthreads();
        As[lk+0][lrow]=a0_r.x; As[lk+1][lrow]=a0_r.y; As[lk+2][lrow]=a0_r.z; As[lk+3][lrow]=a0_r.w;
        As[lk+4][lrow]=a1_r.x; As[lk+5][lrow]=a1_r.y; As[lk+6][lrow]=a1_r.z; As[lk+7][lrow]=a1_r.w;
        Bs[lk+0][lrow]=b0_r.x; Bs[lk+1][lrow]=b0_r.y; Bs[lk+2][lrow]=b0_r.z; Bs[lk+3][lrow]=b0_r.w;
        Bs[lk+4][lrow]=b1_r.x; Bs[lk+5][lrow]=b1_r.y; Bs[lk+6][lrow]=b1_r.z; Bs[lk+7][lrow]=b1_r.w;
        if (kt + BK < H_) {
            a0_n = *(const float4*)&A [(long)(m0 + lrow) * lda + kt + BK + lk];
            a1_n = *(const float4*)&A [(long)(m0 + lrow) * lda + kt + BK + lk + 4];
            b0_n = *(const float4*)&Bm[(long)(n0 + lrow) * ldb + kt + BK + lk];
            b1_n = *(const float4*)&Bm[(long)(n0 + lrow) * ldb + kt + BK + lk + 4];
        }
        __syncthreads();
        #pragma unroll
        for (int kk = 0; kk < BK; ++kk) {
            float4 av = *(const float4*)&As[kk][tm];
            float4 bv = *(const float4*)&Bs[kk][tn];
            float am[4] = {av.x, av.y, av.z, av.w};
            float bn[4] = {bv.x, bv.y, bv.z, bv.w};
            #pragma unroll
            for (int i = 0; i < 4; ++i)
                #pragma unroll
                for (int j = 0; j < 4; ++j)
                    acc[i][j] = fmaf(am[i], bn[j], acc[i][j]);
        }
        a0_r = a0_n; a1_r = a1_n; b0_r = b0_n; b1_r = b1_n;
    }

    if (iskt) {
        // o rows m0+tm..+3 sit inside 8-group (m0+tm)>>3 at offset tm&7 in {0,4}
        const long gbase = ((long)bz * 32 + ((m0 + tm) >> 3)) * PADK * 8 + (tm & 7);
        #pragma unroll
        for (int j = 0; j < 4; ++j) {
            half4_t h4;
            #pragma unroll
            for (int i = 0; i < 4; ++i) {
                float e = __builtin_amdgcn_exp2f(acc[i][j] * TWO_LOG2E);
                h4[i] = (_Float16)fminf(e, 60000.0f);   // fp16-overflow guard
            }
            *(half4_t*)&Ebuf[gbase + (long)(n0 + tn + j) * 8] = h4;
        }
    } else {
        #pragma unroll
        for (int i = 0; i < 4; ++i) {
            float4 f4v = { __builtin_amdgcn_exp2f(acc[i][0] * TWO_LOG2E),
                           __builtin_amdgcn_exp2f(acc[i][1] * TWO_LOG2E),
                           __builtin_amdgcn_exp2f(acc[i][2] * TWO_LOG2E),
                           __builtin_amdgcn_exp2f(acc[i][3] * TWO_LOG2E) };
            *(float4*)&Fbuf[((long)bz * NQ_ + m0 + tm + i) * H_ + n0 + tn] = f4v;
        }
    }
}

// One block per (b, 2 q-rows), 512 threads = one per k.
// prod[q,k] = -2 * sum_h v[h] / (1 + E[h,k]*F[q,h])   (Sum v cancels in LSM)
// r15 ablation: E f32 stream ran at 26.8 TB/s = ~78% of L2 ceiling -> E was
// BANDWIDTH-bound. fp16 E halves bytes (268->134 MB => ~5us) and halves the
// load count (one half8 per 8h). Math in f32 via v_cvt_f32_f16 (full-rate).
// F and v stay wave-uniform s_loads at point of use (manual scalar pipe: null).
__global__ __launch_bounds__(512, 2)
void attn_main(const half8* __restrict__ Eh,   // [B][32][PADK]
               const float* __restrict__ Fbuf, // [B][NQ][H]
               const float* __restrict__ v,    // [H]
               float* __restrict__ out)        // [B][NQ][NK]
{
    const int k = threadIdx.x, b = blockIdx.y, q0 = blockIdx.x * 2;

    const half8* kp   = Eh + (long)b * 32 * PADK + k;
    const float4* F0p = (const float4*)(Fbuf + ((long)b * NQ_ + q0) * H_);
    const float4* F1p = F0p + (H_ / 4);
    const float4* v4p = (const float4*)v;

    float T0 = 0.f, T1 = 0.f;

    // 2-group rotation: compute 4 rows (32 h) while the next 4 load
    half8 ka0 = kp[0*PADK], ka1 = kp[1*PADK], ka2 = kp[2*PADK], ka3 = kp[3*PADK];
    half8 kn0 = ka0, kn1 = ka1, kn2 = ka2, kn3 = ka3;

#define QTERM(T, E0, E1, E2, E3, FQ, VV)                                      \
    {                                                                         \
        float d0 = fmaf(E0, FQ.x, 1.f), d1 = fmaf(E1, FQ.y, 1.f);             \
        float d2 = fmaf(E2, FQ.z, 1.f), d3 = fmaf(E3, FQ.w, 1.f);             \
        float D01 = d0 * d1, D23 = d2 * d3;                                   \
        float N01 = fmaf(VV.x, d1, VV.y * d0);                                \
        float N23 = fmaf(VV.z, d3, VV.w * d2);                                \
        float N   = fmaf(N01, D23, N23 * D01);                                \
        T = fmaf(N, __builtin_amdgcn_rcpf(D01 * D23), T);                     \
    }
// one E row = 8 h values for this k; R = row index (h = 8R..8R+7)
#define PROW(KV, R)                                                           \
    {                                                                         \
        float e0 = (float)KV[0], e1 = (float)KV[1], e2 = (float)KV[2],        \
              e3 = (float)KV[3], e4 = (float)KV[4], e5 = (float)KV[5],        \
              e6 = (float)KV[6], e7 = (float)KV[7];                           \
        float4 va  = v4p[2*(R)],   vb  = v4p[2*(R)+1];                        \
        float4 f0a = F0p[2*(R)],   f0b = F0p[2*(R)+1];                        \
        float4 f1a = F1p[2*(R)],   f1b = F1p[2*(R)+1];                        \
        QTERM(T0, e0, e1, e2, e3, f0a, va)                                    \
        QTERM(T0, e4, e5, e6, e7, f0b, vb)                                    \
        QTERM(T1, e0, e1, e2, e3, f1a, va)                                    \
        QTERM(T1, e4, e5, e6, e7, f1b, vb)                                    \
    }

    for (int g = 0; g < 32; g += 4) {
        if (g + 4 < 32) {          // issue next group's E loads first
            kn0 = kp[(long)(g + 4) * PADK];
            kn1 = kp[(long)(g + 5) * PADK];
            kn2 = kp[(long)(g + 6) * PADK];
            kn3 = kp[(long)(g + 7) * PADK];
        }
        PROW(ka0, g + 0)
        PROW(ka1, g + 1)
        PROW(ka2, g + 2)
        PROW(ka3, g + 3)
        ka0 = kn0; ka1 = kn1; ka2 = kn2; ka3 = kn3;
    }
#undef PROW
#undef QTERM

    float val0 = -2.f * T0;
    float val1 = -2.f * T1;

    // ---- log-softmax over k, no max pass (|val| <= 2*sum|v| ~ 16, safe) ----
    __shared__ float red[8][2];
    const int lane = k & 63, wv = k >> 6;

    float e0 = __builtin_amdgcn_exp2f(val0 * 1.4426950408889634f);
    float e1 = __builtin_amdgcn_exp2f(val1 * 1.4426950408889634f);
    #pragma unroll
    for (int o = 32; o; o >>= 1) {
        e0 += __shfl_xor(e0, o, 64);
        e1 += __shfl_xor(e1, o, 64);
    }
    if (lane == 0) { red[wv][0] = e0; red[wv][1] = e1; }
    __syncthreads();
    float s0 = 0.f, s1 = 0.f;
    #pragma unroll
    for (int w = 0; w < 8; ++w) { s0 += red[w][0]; s1 += red[w][1]; }

    float l0 = __builtin_amdgcn_logf(s0) * 0.6931471805599453f;  // ln(s0)
    float l1 = __builtin_amdgcn_logf(s1) * 0.6931471805599453f;
    out[((long)b * NQ_ + q0 + 0) * NK_ + k] = val0 - l0;
    out[((long)b * NQ_ + q0 + 1) * NK_ + k] = val1 - l1;
}

extern "C" void kernel_launch(void* const* d_in, const int* in_sizes, int n_in,
                              void* d_out, int out_size, void* d_ws, size_t ws_size,
                              hipStream_t stream)
{
    const float* xq = (const float*)d_in[0];  // (4,256,256)
    const float* xk = (const float*)d_in[1];  // (4,512,256)
    const float* w1 = (const float*)d_in[2];  // (256,256) out,in
    const float* w2 = (const float*)d_in[3];  // (256,256)
    const float* v  = (const float*)d_in[4];  // (1,256)
    float* out = (float*)d_out;

    _Float16* Ebuf = (_Float16*)d_ws;                     // [4][32][520][8] fp16 ~1.06MB
    float* Fbuf = (float*)((char*)d_ws + (size_t)B_ * 32 * PADK * 8 * 2);  // 1MB f32

    gemm_fused<<<dim3(192), 256, 0, stream>>>(xq, xk, w1, w2, Ebuf, Fbuf);
    attn_main<<<dim3(NQ_ / 2, B_), 512, 0, stream>>>(
        (const half8*)Ebuf, Fbuf, v, out);
}